// Round 1
// baseline (487.054 us; speedup 1.0000x reference)
//
#include <hip/hip_runtime.h>

#define WID 224
#define HGT 224
#define HWp (224*224)      // 50176
#define CHW (3*224*224)    // 150528
#define NB  64
#define ST  784            // stats stride per image (floats): [0]=mu, [1..3]=lo, [4..6]=hi, [16..783]=lut[3][256]

__device__ __forceinline__ float clip255(float v){ return fminf(fmaxf(v, 0.f), 255.f); }

__global__ void init_kernel(int* maxbits){ *maxbits = 0; }

__global__ void gmax_kernel(const float* __restrict__ x, int n, int* __restrict__ maxbits){
    float m = 0.f;
    for (int i = blockIdx.x*blockDim.x + threadIdx.x; i < n; i += gridDim.x*blockDim.x)
        m = fmaxf(m, x[i]);
    for (int o = 32; o > 0; o >>= 1) m = fmaxf(m, __shfl_down(m, o));
    __shared__ float sm[4];
    int lane = threadIdx.x & 63, wv = threadIdx.x >> 6;
    if (lane == 0) sm[wv] = m;
    __syncthreads();
    if (threadIdx.x == 0){
        float mm = sm[0];
        for (int i = 1; i < (int)blockDim.x/64; i++) mm = fmaxf(mm, sm[i]);
        atomicMax(maxbits, __float_as_int(mm));   // all inputs >= 0 -> int-bit order == float order
    }
}

__global__ void scale_kernel(const int* __restrict__ maxbits, float* __restrict__ scale){
    *scale = (__int_as_float(*maxbits) <= 1.0f) ? 255.f : 1.f;
}

// One block per image. Computes stats only for ops that need them:
// 8=contrast (mean of gray), 11=equalize (per-channel LUT), 12=autocontrast (per-channel min/max)
__global__ void stats_kernel(const float* __restrict__ src,
                             const int* __restrict__ opi,
                             const int* __restrict__ mask,
                             const float* __restrict__ scalePtr,
                             float* __restrict__ stats,
                             int applyScale){
    __shared__ float red[256];
    __shared__ int hist[768];
    int b = blockIdx.x;
    int j = opi[b];
    if (!mask[b]) return;
    if (j != 8 && j != 11 && j != 12) return;
    float scl = applyScale ? *scalePtr : 1.f;
    const float* img = src + (size_t)b * CHW;
    float* st = stats + (size_t)b * ST;
    int tid = threadIdx.x;

    if (j == 8) {                       // contrast: mean of grayscale
        float sum = 0.f;
        for (int p = tid; p < HWp; p += 256){
            float r = img[p], g = img[HWp+p], bl = img[2*HWp+p];
            sum += 0.299f*r + 0.587f*g + 0.114f*bl;
        }
        sum *= scl;
        red[tid] = sum; __syncthreads();
        for (int s = 128; s > 0; s >>= 1){ if (tid < s) red[tid] += red[tid+s]; __syncthreads(); }
        if (tid == 0) st[0] = red[0] * (1.f/(float)HWp);
    } else if (j == 11) {               // equalize: per-channel histogram -> LUT
        for (int i = tid; i < 768; i += 256) hist[i] = 0;
        __syncthreads();
        for (int i = tid; i < CHW; i += 256){
            int c = i / HWp;
            float v = img[i] * scl;
            int iv = (int)rintf(v);
            iv = min(max(iv, 0), 255);
            atomicAdd(&hist[c*256 + iv], 1);
        }
        __syncthreads();
        if (tid < 3){
            const int* h = hist + tid*256;
            int step = (HWp - h[255]) / 255;
            int cum = 0;                           // exclusive cumsum
            float* lut = st + 16 + tid*256;
            for (int i = 0; i < 256; i++){
                int l;
                if (step > 0){ l = (cum + (step >> 1)) / step; l = min(max(l, 0), 255); }
                else l = i;
                lut[i] = (float)l;
                cum += h[i];
            }
        }
    } else {                            // autocontrast: per-channel min/max
        for (int c = 0; c < 3; c++){
            const float* pl = img + c*HWp;
            float lo = 3.4e38f, hi = -3.4e38f;
            for (int p = tid; p < HWp; p += 256){
                float v = pl[p] * scl;
                lo = fminf(lo, v); hi = fmaxf(hi, v);
            }
            red[tid] = lo; __syncthreads();
            for (int s = 128; s > 0; s >>= 1){ if (tid < s) red[tid] = fminf(red[tid], red[tid+s]); __syncthreads(); }
            if (tid == 0) st[1+c] = red[0];
            __syncthreads();
            red[tid] = hi; __syncthreads();
            for (int s = 128; s > 0; s >>= 1){ if (tid < s) red[tid] = fmaxf(red[tid], red[tid+s]); __syncthreads(); }
            if (tid == 0) st[4+c] = red[0];
            __syncthreads();
        }
    }
}

__device__ __forceinline__ float samp(const float* __restrict__ pl, float yi, float xi, float scl){
    if (xi < 0.f || xi > (float)(WID-1) || yi < 0.f || yi > (float)(HGT-1)) return 0.f;
    return pl[(int)yi * WID + (int)xi] * scl;
}

__global__ void apply_kernel(const float* __restrict__ src,
                             float* __restrict__ dst,
                             const int* __restrict__ opi,
                             const float* __restrict__ mags,
                             const int* __restrict__ mask,
                             const float* __restrict__ scalePtr,
                             const float* __restrict__ stats,
                             int applyScale, int finalOut){
    int idx = blockIdx.x*256 + threadIdx.x;
    int b = idx / CHW;
    int r = idx - b*CHW;
    int c = r / HWp;
    int p = r - c*HWp;
    int y = p / WID;
    int x = p - y*WID;
    float scl = applyScale ? *scalePtr : 1.f;
    const float* img = src + (size_t)b * CHW;
    const float* pl  = img + c*HWp;
    float inv = pl[p] * scl;
    int   j  = opi[b];
    int   ap = mask[b];
    float m  = mags[b];
    const float* st = stats + (size_t)b * ST;
    float out;
    if (!ap) {
        out = inv;
    } else {
        switch (j){
        case 0: case 1: case 2: case 3: case 4: {   // affine family
            float a = 1.f, bb = 0.f, cc = 0.f, dd = 0.f, ee = 1.f, ff = 0.f;
            if (j == 0)      bb = -0.3f + 0.6f*m;                       // shear_x
            else if (j == 1) dd = -0.3f + 0.6f*m;                       // shear_y
            else if (j == 2) cc = (-0.45f + 0.9f*m) * (float)WID;       // translate_x
            else if (j == 3) ff = (-0.45f + 0.9f*m) * (float)HGT;       // translate_y
            else {                                                      // rotate
                float deg = -30.f + 60.f*m;
                float rad = deg * (float)(3.14159265358979323846/180.0);
                float cs = cosf(rad), sn = sinf(rad);
                float cx = (WID-1)*0.5f, cy = (HGT-1)*0.5f;
                a = cs; bb = sn; dd = -sn; ee = cs;
                cc = cx - cs*cx - sn*cy;
                ff = cy + sn*cx - cs*cy;
            }
            float xf = (float)x, yf = (float)y;
            float sx = a*xf + bb*yf + cc;
            float sy = dd*xf + ee*yf + ff;
            float x0f = floorf(sx), y0f = floorf(sy);
            float wx = sx - x0f, wy = sy - y0f;
            float v00 = samp(pl, y0f,     x0f,     scl);
            float v01 = samp(pl, y0f,     x0f+1.f, scl);
            float v10 = samp(pl, y0f+1.f, x0f,     scl);
            float v11 = samp(pl, y0f+1.f, x0f+1.f, scl);
            float top = v00*(1.f-wx) + v01*wx;
            float bot = v10*(1.f-wx) + v11*wx;
            out = top*(1.f-wy) + bot*wy;
            break; }
        case 5:  out = clip255(inv * (0.1f + 1.8f*m)); break;           // brightness
        case 6: {                                                       // color
            float rr = img[p]*scl, gg = img[HWp+p]*scl, bl = img[2*HWp+p]*scl;
            float g = 0.299f*rr + 0.587f*gg + 0.114f*bl;
            out = clip255(g + (0.1f + 1.8f*m)*(inv - g));
            break; }
        case 7: {                                                       // sharpness
            if (y == 0 || y == HGT-1 || x == 0 || x == WID-1) out = inv;
            else {
                float s8 = pl[p-WID-1] + pl[p-WID] + pl[p-WID+1]
                         + pl[p-1]     + pl[p+1]
                         + pl[p+WID-1] + pl[p+WID] + pl[p+WID+1];
                float blur = (s8*scl + 5.f*inv) * (1.f/13.f);
                out = clip255(blur + (0.1f + 1.8f*m)*(inv - blur));
            }
            break; }
        case 8: {                                                       // contrast
            float mu = st[0];
            out = clip255(mu + (0.1f + 1.8f*m)*(inv - mu));
            break; }
        case 9: {                                                       // solarize
            float thr = 256.f*m;
            out = (inv < thr) ? inv : 255.f - inv;
            break; }
        case 10: {                                                      // posterize
            float nb = rintf(4.f*m);
            float q  = exp2f(nb);
            out = floorf(inv/q)*q;
            break; }
        case 11: {                                                      // equalize
            int iv = min(max((int)rintf(inv), 0), 255);
            out = st[16 + c*256 + iv];
            break; }
        case 12: {                                                      // autocontrast
            float lo = st[1+c], hi = st[4+c];
            if (hi > lo) out = clip255((inv - lo) * (255.f / fmaxf(hi - lo, 1e-6f)));
            else out = inv;
            break; }
        default: out = inv; break;                                      // identity
        }
    }
    if (finalOut) dst[idx] = fminf(fmaxf(out * (1.f/255.f), 0.f), 1.f);
    else          dst[idx] = out;
}

extern "C" void kernel_launch(void* const* d_in, const int* in_sizes, int n_in,
                              void* d_out, int out_size, void* d_ws, size_t ws_size,
                              hipStream_t stream) {
    const float* x    = (const float*)d_in[0];
    const float* ra   = (const float*)d_in[1];
    const int*   op   = (const int*)d_in[2];
    const int*   mask = (const int*)d_in[3];
    float* out = (float*)d_out;

    float* wsf     = (float*)d_ws;
    int*   maxbits = (int*)wsf;          // [0]
    float* scale   = wsf + 1;            // [1]
    float* stats   = wsf + 16;           // [16 .. 16+64*784)
    float* inter   = wsf + 65536;        // intermediate image buffer (38.5 MB)

    const int N = NB * CHW;              // 9,633,792

    init_kernel <<<1, 1, 0, stream>>>(maxbits);
    gmax_kernel <<<1024, 256, 0, stream>>>(x, N, maxbits);
    scale_kernel<<<1, 1, 0, stream>>>(maxbits, scale);

    // depth 0: src = x (scaled on the fly), dst = inter
    stats_kernel<<<NB, 256, 0, stream>>>(x, op, mask, scale, stats, 1);
    apply_kernel<<<N/256, 256, 0, stream>>>(x, inter, op, ra, mask, scale, stats, 1, 0);

    // depth 1: src = inter, dst = out (with /255 + clip epilogue)
    stats_kernel<<<NB, 256, 0, stream>>>(inter, op + NB, mask + NB, scale, stats, 0);
    apply_kernel<<<N/256, 256, 0, stream>>>(inter, out, op + NB, ra + NB, mask + NB, scale, stats, 0, 1);
}

// Round 2
// 185.488 us; speedup vs baseline: 2.6258x; 2.6258x over previous
//
#include <hip/hip_runtime.h>

#define WID 224
#define HGT 224
#define HWp (224*224)      // 50176
#define CHW (3*224*224)    // 150528
#define NB  64
#define ST  784            // per-image stats: [0]=mu, [1..3]=lo, [4..6]=hi, [16..783]=lut[3][256]
#define SPLIT 32
#define CHUNK (HWp/SPLIT)  // 1568

__device__ __forceinline__ float clip255(float v){ return fminf(fmaxf(v, 0.f), 255.f); }

__global__ void init_kernel(int* maxbits){ *maxbits = 0; }

__global__ void gmax_kernel(const float4* __restrict__ x, int n4, int* __restrict__ maxbits){
    float m = 0.f;
    for (int i = blockIdx.x*blockDim.x + threadIdx.x; i < n4; i += gridDim.x*blockDim.x){
        float4 v = x[i];
        m = fmaxf(m, fmaxf(fmaxf(v.x, v.y), fmaxf(v.z, v.w)));
    }
    for (int o = 32; o > 0; o >>= 1) m = fmaxf(m, __shfl_down(m, o));
    __shared__ float sm[4];
    int lane = threadIdx.x & 63, wv = threadIdx.x >> 6;
    if (lane == 0) sm[wv] = m;
    __syncthreads();
    if (threadIdx.x == 0){
        float mm = sm[0];
        for (int i = 1; i < (int)blockDim.x/64; i++) mm = fmaxf(mm, sm[i]);
        atomicMax(maxbits, __float_as_int(mm));   // inputs >= 0 -> int-bit order == float order
    }
}

__global__ void scale_kernel(const int* __restrict__ maxbits, float* __restrict__ scale){
    *scale = (__int_as_float(*maxbits) <= 1.0f) ? 255.f : 1.f;
}

__global__ void init_stats(float* __restrict__ sums, int* __restrict__ lobits,
                           int* __restrict__ hibits, int* __restrict__ hist){
    int i = blockIdx.x*256 + threadIdx.x;
    if (i < NB) sums[i] = 0.f;
    if (i < NB*3){ lobits[i] = 0x7F7FFFFF; hibits[i] = 0; }
    for (int h = i; h < NB*768; h += gridDim.x*256) hist[h] = 0;
}

// grid = NB*SPLIT blocks; block handles pixels [s*CHUNK, (s+1)*CHUNK) of image b.
__global__ void stats_part(const float* __restrict__ src,
                           const int* __restrict__ opi,
                           const int* __restrict__ mask,
                           const float* __restrict__ scalePtr,
                           float* __restrict__ sums,
                           int* __restrict__ lobits,
                           int* __restrict__ hibits,
                           int* __restrict__ hist,
                           int applyScale){
    __shared__ float red[256];
    __shared__ int sh[768];
    int b = blockIdx.x / SPLIT;
    int s = blockIdx.x & (SPLIT-1);
    int j = opi[b];
    if (!mask[b]) return;
    if (j != 8 && j != 11 && j != 12) return;
    float scl = applyScale ? *scalePtr : 1.f;
    const float* img = src + (size_t)b * CHW;
    int tid = threadIdx.x;
    int p0 = s * CHUNK;

    if (j == 8) {                       // contrast: partial sum of grayscale
        float sum = 0.f;
        for (int p = p0 + tid*4; p < p0 + CHUNK; p += 1024){
            float4 r  = *(const float4*)(img + p);
            float4 g  = *(const float4*)(img + HWp + p);
            float4 bl = *(const float4*)(img + 2*HWp + p);
            sum += 0.299f*(r.x+r.y+r.z+r.w) + 0.587f*(g.x+g.y+g.z+g.w) + 0.114f*(bl.x+bl.y+bl.z+bl.w);
        }
        red[tid] = sum; __syncthreads();
        for (int t = 128; t > 0; t >>= 1){ if (tid < t) red[tid] += red[tid+t]; __syncthreads(); }
        if (tid == 0) atomicAdd(&sums[b], red[0] * scl);
    } else if (j == 11) {               // equalize: shared hist -> global hist
        for (int i = tid; i < 768; i += 256) sh[i] = 0;
        __syncthreads();
        for (int c = 0; c < 3; c++){
            const float* pl = img + c*HWp;
            for (int p = p0 + tid; p < p0 + CHUNK; p += 256){
                int iv = (int)rintf(pl[p] * scl);
                iv = min(max(iv, 0), 255);
                atomicAdd(&sh[c*256 + iv], 1);
            }
        }
        __syncthreads();
        for (int i = tid; i < 768; i += 256){
            int v = sh[i];
            if (v) atomicAdd(&hist[b*768 + i], v);
        }
    } else {                            // autocontrast: partial min/max per channel
        for (int c = 0; c < 3; c++){
            const float* pl = img + c*HWp;
            float lo = 3.4e38f, hi = 0.f;
            for (int p = p0 + tid*4; p < p0 + CHUNK; p += 1024){
                float4 v = *(const float4*)(pl + p);
                lo = fminf(lo, fminf(fminf(v.x,v.y), fminf(v.z,v.w)));
                hi = fmaxf(hi, fmaxf(fmaxf(v.x,v.y), fmaxf(v.z,v.w)));
            }
            red[tid] = lo; __syncthreads();
            for (int t = 128; t > 0; t >>= 1){ if (tid < t) red[tid] = fminf(red[tid], red[tid+t]); __syncthreads(); }
            if (tid == 0) atomicMin(&lobits[b*3+c], __float_as_int(red[0] * scl));
            __syncthreads();
            red[tid] = hi; __syncthreads();
            for (int t = 128; t > 0; t >>= 1){ if (tid < t) red[tid] = fmaxf(red[tid], red[tid+t]); __syncthreads(); }
            if (tid == 0) atomicMax(&hibits[b*3+c], __float_as_int(red[0] * scl));
            __syncthreads();
        }
    }
}

__global__ void stats_final(const int* __restrict__ opi,
                            const int* __restrict__ mask,
                            const float* __restrict__ sums,
                            const int* __restrict__ lobits,
                            const int* __restrict__ hibits,
                            const int* __restrict__ hist,
                            float* __restrict__ stats){
    __shared__ int sh[768];
    int b = blockIdx.x;
    int j = opi[b];
    if (!mask[b]) return;
    int tid = threadIdx.x;
    float* st = stats + (size_t)b * ST;
    if (j == 8){
        if (tid == 0) st[0] = sums[b] * (1.f/(float)HWp);
    } else if (j == 12){
        if (tid < 3){
            st[1+tid] = __int_as_float(lobits[b*3+tid]);
            st[4+tid] = __int_as_float(hibits[b*3+tid]);
        }
    } else if (j == 11){
        for (int i = tid; i < 768; i += 256) sh[i] = hist[b*768 + i];
        __syncthreads();
        if (tid < 3){
            const int* h = sh + tid*256;
            int step = (HWp - h[255]) / 255;
            int cum = 0;                           // exclusive cumsum
            float* lut = st + 16 + tid*256;
            for (int i = 0; i < 256; i++){
                int l = (step > 0) ? min(max((cum + (step >> 1)) / step, 0), 255) : i;
                lut[i] = (float)l;
                cum += h[i];
            }
        }
    }
}

__device__ __forceinline__ float samp(const float* __restrict__ pl, float yi, float xi, float scl){
    if (xi < 0.f || xi > (float)(WID-1) || yi < 0.f || yi > (float)(HGT-1)) return 0.f;
    return pl[(int)yi * WID + (int)xi] * scl;
}

// 4 pixels per thread (float4); grid = NB*CHW/1024 blocks of 256
__global__ void apply_kernel(const float* __restrict__ src,
                             float* __restrict__ dst,
                             const int* __restrict__ opi,
                             const float* __restrict__ mags,
                             const int* __restrict__ mask,
                             const float* __restrict__ scalePtr,
                             const float* __restrict__ stats,
                             int applyScale, int finalOut){
    int idx = (blockIdx.x*256 + threadIdx.x) * 4;
    int b = idx / CHW;
    int r = idx - b*CHW;
    int c = r / HWp;
    int p = r - c*HWp;
    int y = p / WID;
    int x = p - y*WID;
    float scl = applyScale ? *scalePtr : 1.f;
    const float* img = src + (size_t)b * CHW;
    const float* pl  = img + c*HWp;
    float4 v4 = *(const float4*)(pl + p);
    float iv[4] = {v4.x*scl, v4.y*scl, v4.z*scl, v4.w*scl};
    int   j  = opi[b];
    int   ap = mask[b];
    float m  = mags[b];
    const float* st = stats + (size_t)b * ST;
    float o[4];

    if (!ap) {
        #pragma unroll
        for (int k = 0; k < 4; k++) o[k] = iv[k];
    } else {
        switch (j){
        case 0: case 1: case 2: case 3: case 4: {   // affine family
            float a = 1.f, bb = 0.f, cc = 0.f, dd = 0.f, ee = 1.f, ff = 0.f;
            if (j == 0)      bb = -0.3f + 0.6f*m;
            else if (j == 1) dd = -0.3f + 0.6f*m;
            else if (j == 2) cc = (-0.45f + 0.9f*m) * (float)WID;
            else if (j == 3) ff = (-0.45f + 0.9f*m) * (float)HGT;
            else {
                float deg = -30.f + 60.f*m;
                float rad = deg * (float)(3.14159265358979323846/180.0);
                float cs = cosf(rad), sn = sinf(rad);
                float cx = (WID-1)*0.5f, cy = (HGT-1)*0.5f;
                a = cs; bb = sn; dd = -sn; ee = cs;
                cc = cx - cs*cx - sn*cy;
                ff = cy + sn*cx - cs*cy;
            }
            float yf = (float)y;
            #pragma unroll
            for (int k = 0; k < 4; k++){
                float xf = (float)(x + k);
                float sx = a*xf + bb*yf + cc;
                float sy = dd*xf + ee*yf + ff;
                float x0f = floorf(sx), y0f = floorf(sy);
                float wx = sx - x0f, wy = sy - y0f;
                float v00 = samp(pl, y0f,     x0f,     scl);
                float v01 = samp(pl, y0f,     x0f+1.f, scl);
                float v10 = samp(pl, y0f+1.f, x0f,     scl);
                float v11 = samp(pl, y0f+1.f, x0f+1.f, scl);
                float top = v00*(1.f-wx) + v01*wx;
                float bot = v10*(1.f-wx) + v11*wx;
                o[k] = top*(1.f-wy) + bot*wy;
            }
            break; }
        case 5: {                                                       // brightness
            float f = 0.1f + 1.8f*m;
            #pragma unroll
            for (int k = 0; k < 4; k++) o[k] = clip255(iv[k]*f);
            break; }
        case 6: {                                                       // color
            float4 r4 = *(const float4*)(img + p);
            float4 g4 = *(const float4*)(img + HWp + p);
            float4 b4 = *(const float4*)(img + 2*HWp + p);
            float rr[4] = {r4.x*scl, r4.y*scl, r4.z*scl, r4.w*scl};
            float gg[4] = {g4.x*scl, g4.y*scl, g4.z*scl, g4.w*scl};
            float bl[4] = {b4.x*scl, b4.y*scl, b4.z*scl, b4.w*scl};
            float f = 0.1f + 1.8f*m;
            #pragma unroll
            for (int k = 0; k < 4; k++){
                float g = 0.299f*rr[k] + 0.587f*gg[k] + 0.114f*bl[k];
                o[k] = clip255(g + f*(iv[k] - g));
            }
            break; }
        case 7: {                                                       // sharpness
            float f = 0.1f + 1.8f*m;
            #pragma unroll
            for (int k = 0; k < 4; k++){
                int xx = x + k;
                if (y == 0 || y == HGT-1 || xx == 0 || xx == WID-1) o[k] = iv[k];
                else {
                    int q = p + k;
                    float s8 = pl[q-WID-1] + pl[q-WID] + pl[q-WID+1]
                             + pl[q-1]     + pl[q+1]
                             + pl[q+WID-1] + pl[q+WID] + pl[q+WID+1];
                    float blur = (s8*scl + 5.f*iv[k]) * (1.f/13.f);
                    o[k] = clip255(blur + f*(iv[k] - blur));
                }
            }
            break; }
        case 8: {                                                       // contrast
            float mu = st[0];
            float f = 0.1f + 1.8f*m;
            #pragma unroll
            for (int k = 0; k < 4; k++) o[k] = clip255(mu + f*(iv[k] - mu));
            break; }
        case 9: {                                                       // solarize
            float thr = 256.f*m;
            #pragma unroll
            for (int k = 0; k < 4; k++) o[k] = (iv[k] < thr) ? iv[k] : 255.f - iv[k];
            break; }
        case 10: {                                                      // posterize
            float q = exp2f(rintf(4.f*m));
            #pragma unroll
            for (int k = 0; k < 4; k++) o[k] = floorf(iv[k]/q)*q;
            break; }
        case 11: {                                                      // equalize
            #pragma unroll
            for (int k = 0; k < 4; k++){
                int ivi = min(max((int)rintf(iv[k]), 0), 255);
                o[k] = st[16 + c*256 + ivi];
            }
            break; }
        case 12: {                                                      // autocontrast
            float lo = st[1+c], hi = st[4+c];
            float sc = 255.f / fmaxf(hi - lo, 1e-6f);
            #pragma unroll
            for (int k = 0; k < 4; k++)
                o[k] = (hi > lo) ? clip255((iv[k] - lo) * sc) : iv[k];
            break; }
        default:
            #pragma unroll
            for (int k = 0; k < 4; k++) o[k] = iv[k];
            break;
        }
    }

    float4 w;
    if (finalOut){
        w.x = fminf(fmaxf(o[0]*(1.f/255.f), 0.f), 1.f);
        w.y = fminf(fmaxf(o[1]*(1.f/255.f), 0.f), 1.f);
        w.z = fminf(fmaxf(o[2]*(1.f/255.f), 0.f), 1.f);
        w.w = fminf(fmaxf(o[3]*(1.f/255.f), 0.f), 1.f);
    } else {
        w.x = o[0]; w.y = o[1]; w.z = o[2]; w.w = o[3];
    }
    *(float4*)(dst + idx) = w;
}

extern "C" void kernel_launch(void* const* d_in, const int* in_sizes, int n_in,
                              void* d_out, int out_size, void* d_ws, size_t ws_size,
                              hipStream_t stream) {
    const float* x    = (const float*)d_in[0];
    const float* ra   = (const float*)d_in[1];
    const int*   op   = (const int*)d_in[2];
    const int*   mask = (const int*)d_in[3];
    float* out = (float*)d_out;

    float* wsf     = (float*)d_ws;
    int*   maxbits = (int*)wsf;                 // [0]
    float* scale   = wsf + 1;                   // [1]
    float* sums    = wsf + 64;                  // [64..128)
    int*   lobits  = (int*)(wsf + 128);         // [128..320)
    int*   hibits  = (int*)(wsf + 320);         // [320..512)
    int*   hist    = (int*)(wsf + 512);         // [512..49664)
    float* stats   = wsf + 49664;               // [49664..99840)
    float* inter   = wsf + 99840;               // intermediate image (38.5 MB)

    const int N = NB * CHW;                     // 9,633,792

    init_kernel <<<1, 1, 0, stream>>>(maxbits);
    gmax_kernel <<<1024, 256, 0, stream>>>((const float4*)x, N/4, maxbits);
    scale_kernel<<<1, 1, 0, stream>>>(maxbits, scale);

    // depth 0: src = x (scaled on the fly), dst = inter
    init_stats <<<64, 256, 0, stream>>>(sums, lobits, hibits, hist);
    stats_part <<<NB*SPLIT, 256, 0, stream>>>(x, op, mask, scale, sums, lobits, hibits, hist, 1);
    stats_final<<<NB, 256, 0, stream>>>(op, mask, sums, lobits, hibits, hist, stats);
    apply_kernel<<<N/1024, 256, 0, stream>>>(x, inter, op, ra, mask, scale, stats, 1, 0);

    // depth 1: src = inter, dst = out (with /255 + clip epilogue)
    init_stats <<<64, 256, 0, stream>>>(sums, lobits, hibits, hist);
    stats_part <<<NB*SPLIT, 256, 0, stream>>>(inter, op + NB, mask + NB, scale, sums, lobits, hibits, hist, 0);
    stats_final<<<NB, 256, 0, stream>>>(op + NB, mask + NB, sums, lobits, hibits, hist, stats);
    apply_kernel<<<N/1024, 256, 0, stream>>>(inter, out, op + NB, ra + NB, mask + NB, scale, stats, 0, 1);
}

// Round 3
// 163.658 us; speedup vs baseline: 2.9760x; 1.1334x over previous
//
#include <hip/hip_runtime.h>

#define WID 224
#define HGT 224
#define HWp (224*224)      // 50176
#define CHW (3*224*224)    // 150528
#define NB  64
#define ST  784            // per-image stats: [0]=mu, [1..3]=lo, [4..6]=hi, [16..783]=lut[3][256]
#define SPLIT 32
#define CHUNK (HWp/SPLIT)  // 1568
#define BPI (CHW/1024)     // 147 apply-blocks per image
#define BPC (HWp/1024)     // 49 apply-blocks per channel

__device__ __forceinline__ float clip255(float v){ return fminf(fmaxf(v, 0.f), 255.f); }

__device__ __forceinline__ float blk_reduce(float v, float* red, int tid, int op){
    // op: 0=sum 1=min 2=max
    red[tid] = v; __syncthreads();
    for (int s = 128; s > 0; s >>= 1){
        if (tid < s){
            float a = red[tid], b = red[tid+s];
            red[tid] = (op==0) ? a+b : (op==1 ? fminf(a,b) : fmaxf(a,b));
        }
        __syncthreads();
    }
    float r = red[0]; __syncthreads();
    return r;
}

// ---------------- pass 0: global max + per-image stats0 partials (one read of x) ----------------
// grid = NB*SPLIT = 2048 blocks of 256
__global__ void pass0_kernel(const float* __restrict__ x,
                             const int* __restrict__ op0,
                             const int* __restrict__ mask0,
                             float* __restrict__ pmaxA,   // [2048] partial global max
                             float* __restrict__ psum0,   // [2048] partial gray sum (unscaled)
                             float* __restrict__ pmin0,   // [2048*3]
                             float* __restrict__ pmax0,   // [2048*3]
                             int*   __restrict__ phist0,  // [2048*1536] dual hist (d0:×1, d1:×255)
                             int*   __restrict__ hist1){  // [NB*768] zeroed here for pass 1
    __shared__ float red[256];
    __shared__ int sh[1536];
    int blk = blockIdx.x;
    int b = blk >> 5, s = blk & 31;
    int tid = threadIdx.x;
    // zero depth-1 hist accumulators: 49152 ints / 2048 blocks = 24 each
    if (tid < 24) hist1[blk*24 + tid] = 0;

    int j = op0[b];
    int ap = mask0[b];
    bool needSum  = ap && (j == 8);
    bool needMM   = ap && (j == 12);
    bool needHist = ap && (j == 11);
    const float* img = x + (size_t)b * CHW;
    int p0 = s * CHUNK;
    const float GW[3] = {0.299f, 0.587f, 0.114f};

    float mx = 0.f, gs = 0.f;
    for (int c = 0; c < 3; c++){
        const float* pl = img + c*HWp + p0;
        float lo = 3.4e38f, hi = 0.f, csum = 0.f;
        for (int p = tid*4; p < CHUNK; p += 1024){
            float4 v = *(const float4*)(pl + p);
            float m4 = fmaxf(fmaxf(v.x, v.y), fmaxf(v.z, v.w));
            mx = fmaxf(mx, m4);
            if (needMM){ hi = fmaxf(hi, m4); lo = fminf(lo, fminf(fminf(v.x,v.y), fminf(v.z,v.w))); }
            if (needSum) csum += (v.x + v.y) + (v.z + v.w);
        }
        if (needSum) gs += GW[c] * csum;
        if (needMM){
            float l = blk_reduce(lo, red, tid, 1);
            if (tid == 0) pmin0[blk*3 + c] = l;
            float h = blk_reduce(hi, red, tid, 2);
            if (tid == 0) pmax0[blk*3 + c] = h;
        }
    }
    float bm = blk_reduce(mx, red, tid, 2);
    if (tid == 0) pmaxA[blk] = bm;
    if (needSum){
        float t = blk_reduce(gs, red, tid, 0);
        if (tid == 0) psum0[blk] = t;
    }
    if (needHist){
        for (int i = tid; i < 1536; i += 256) sh[i] = 0;
        __syncthreads();
        for (int c = 0; c < 3; c++){
            const float* pl = img + c*HWp + p0;
            for (int p = tid; p < CHUNK; p += 256){
                float v = pl[p];
                int b0 = min(max((int)rintf(v), 0), 255);
                int b1 = min(max((int)rintf(v*255.f), 0), 255);
                atomicAdd(&sh[c*256 + b0], 1);
                atomicAdd(&sh[768 + c*256 + b1], 1);
            }
        }
        __syncthreads();
        for (int i = tid; i < 1536; i += 256) phist0[blk*1536 + i] = sh[i];
    }
}

// ---------------- finalize 0: scale + stats0 ----------------
__device__ __forceinline__ void build_lut(const int* h, float* lut){
    int step = (HWp - h[255]) / 255;
    int cum = 0;                                   // exclusive cumsum
    for (int i = 0; i < 256; i++){
        int l = (step > 0) ? min(max((cum + (step >> 1)) / step, 0), 255) : i;
        lut[i] = (float)l;
        cum += h[i];
    }
}

__global__ void fin0_kernel(const int* __restrict__ op0,
                            const int* __restrict__ mask0,
                            const float* __restrict__ pmaxA,
                            const float* __restrict__ psum0,
                            const float* __restrict__ pmin0,
                            const float* __restrict__ pmax0,
                            const int*   __restrict__ phist0,
                            float* __restrict__ scalePtr,
                            float* __restrict__ stats0){
    __shared__ float red[256];
    __shared__ int h[768];
    __shared__ float sscale;
    int b = blockIdx.x, tid = threadIdx.x;
    float m = 0.f;
    for (int i = tid; i < NB*SPLIT; i += 256) m = fmaxf(m, pmaxA[i]);
    float gm = blk_reduce(m, red, tid, 2);
    if (tid == 0){
        sscale = (gm <= 1.0f) ? 255.f : 1.f;
        if (b == 0) *scalePtr = sscale;
    }
    __syncthreads();
    float scl = sscale;
    int j = op0[b];
    if (!mask0[b]) return;
    float* st = stats0 + (size_t)b * ST;
    if (j == 8){
        if (tid == 0){
            float t = 0.f;
            for (int s = 0; s < SPLIT; s++) t += psum0[b*SPLIT + s];
            st[0] = t * scl * (1.f/(float)HWp);
        }
    } else if (j == 12){
        if (tid < 3){
            float lo = 3.4e38f, hi = 0.f;
            for (int s = 0; s < SPLIT; s++){
                lo = fminf(lo, pmin0[(b*SPLIT+s)*3 + tid]);
                hi = fmaxf(hi, pmax0[(b*SPLIT+s)*3 + tid]);
            }
            st[1+tid] = lo * scl;
            st[4+tid] = hi * scl;
        }
    } else if (j == 11){
        int d = (scl == 255.f) ? 1 : 0;
        for (int i = tid; i < 768; i += 256){
            int t = 0;
            for (int s = 0; s < SPLIT; s++) t += phist0[(b*SPLIT+s)*1536 + d*768 + i];
            h[i] = t;
        }
        __syncthreads();
        if (tid < 3) build_lut(h + tid*256, st + 16 + tid*256);
    }
}

// ---------------- finalize 1: stats1 from apply0's fused partials ----------------
__global__ void fin1_kernel(const int* __restrict__ op1,
                            const int* __restrict__ mask1,
                            const float* __restrict__ psum1,  // [NB*BPI] gray-weighted block sums
                            const float* __restrict__ pmin1,  // [NB*BPI]
                            const float* __restrict__ pmax1,  // [NB*BPI]
                            const int*   __restrict__ hist1,  // [NB*768]
                            float* __restrict__ stats1){
    __shared__ float red[256];
    __shared__ int h[768];
    int b = blockIdx.x, tid = threadIdx.x;
    int j = op1[b];
    if (!mask1[b]) return;
    float* st = stats1 + (size_t)b * ST;
    if (j == 8){
        float t = 0.f;
        for (int i = tid; i < BPI; i += 256) t += psum1[b*BPI + i];
        float tot = blk_reduce(t, red, tid, 0);
        if (tid == 0) st[0] = tot * (1.f/(float)HWp);
    } else if (j == 12){
        if (tid < 3){
            float lo = 3.4e38f, hi = 0.f;
            for (int k = 0; k < BPC; k++){
                lo = fminf(lo, pmin1[b*BPI + tid*BPC + k]);
                hi = fmaxf(hi, pmax1[b*BPI + tid*BPC + k]);
            }
            st[1+tid] = lo;
            st[4+tid] = hi;
        }
    } else if (j == 11){
        for (int i = tid; i < 768; i += 256) h[i] = hist1[b*768 + i];
        __syncthreads();
        if (tid < 3) build_lut(h + tid*256, st + 16 + tid*256);
    }
}

// ---------------- apply: 4 px/thread; optional fused stats accumulation on outputs ----------------
__device__ __forceinline__ float samp(const float* __restrict__ pl, float yi, float xi, float scl){
    if (xi < 0.f || xi > (float)(WID-1) || yi < 0.f || yi > (float)(HGT-1)) return 0.f;
    return pl[(int)yi * WID + (int)xi] * scl;
}

__global__ void apply_kernel(const float* __restrict__ src,
                             float* __restrict__ dst,
                             const int* __restrict__ opi,
                             const float* __restrict__ mags,
                             const int* __restrict__ mask,
                             const float* __restrict__ scalePtr,
                             const float* __restrict__ stats,
                             const int* __restrict__ opiN,   // next-depth op/mask (doStats)
                             const int* __restrict__ maskN,
                             float* __restrict__ psumN,
                             float* __restrict__ pminN,
                             float* __restrict__ pmaxN,
                             int*   __restrict__ histN,
                             int applyScale, int finalOut, int doStats){
    __shared__ float red[256];
    __shared__ int sh[256];
    int idx = (blockIdx.x*256 + threadIdx.x) * 4;
    int tid = threadIdx.x;
    int b = idx / CHW;
    int r = idx - b*CHW;
    int c = r / HWp;
    int p = r - c*HWp;
    int y = p / WID;
    int x = p - y*WID;
    float scl = applyScale ? *scalePtr : 1.f;
    const float* img = src + (size_t)b * CHW;
    const float* pl  = img + c*HWp;
    float4 v4 = *(const float4*)(pl + p);
    float iv[4] = {v4.x*scl, v4.y*scl, v4.z*scl, v4.w*scl};
    int   j  = opi[b];
    int   ap = mask[b];
    float m  = mags[b];
    const float* st = stats + (size_t)b * ST;
    float o[4];

    if (!ap) {
        #pragma unroll
        for (int k = 0; k < 4; k++) o[k] = iv[k];
    } else {
        switch (j){
        case 0: case 1: case 2: case 3: case 4: {   // affine family
            float a = 1.f, bb = 0.f, cc = 0.f, dd = 0.f, ee = 1.f, ff = 0.f;
            if (j == 0)      bb = -0.3f + 0.6f*m;
            else if (j == 1) dd = -0.3f + 0.6f*m;
            else if (j == 2) cc = (-0.45f + 0.9f*m) * (float)WID;
            else if (j == 3) ff = (-0.45f + 0.9f*m) * (float)HGT;
            else {
                float deg = -30.f + 60.f*m;
                float rad = deg * (float)(3.14159265358979323846/180.0);
                float cs = cosf(rad), sn = sinf(rad);
                float cx = (WID-1)*0.5f, cy = (HGT-1)*0.5f;
                a = cs; bb = sn; dd = -sn; ee = cs;
                cc = cx - cs*cx - sn*cy;
                ff = cy + sn*cx - cs*cy;
            }
            float yf = (float)y;
            #pragma unroll
            for (int k = 0; k < 4; k++){
                float xf = (float)(x + k);
                float sx = a*xf + bb*yf + cc;
                float sy = dd*xf + ee*yf + ff;
                float x0f = floorf(sx), y0f = floorf(sy);
                float wx = sx - x0f, wy = sy - y0f;
                float v00 = samp(pl, y0f,     x0f,     scl);
                float v01 = samp(pl, y0f,     x0f+1.f, scl);
                float v10 = samp(pl, y0f+1.f, x0f,     scl);
                float v11 = samp(pl, y0f+1.f, x0f+1.f, scl);
                float top = v00*(1.f-wx) + v01*wx;
                float bot = v10*(1.f-wx) + v11*wx;
                o[k] = top*(1.f-wy) + bot*wy;
            }
            break; }
        case 5: {
            float f = 0.1f + 1.8f*m;
            #pragma unroll
            for (int k = 0; k < 4; k++) o[k] = clip255(iv[k]*f);
            break; }
        case 6: {
            float4 r4 = *(const float4*)(img + p);
            float4 g4 = *(const float4*)(img + HWp + p);
            float4 b4 = *(const float4*)(img + 2*HWp + p);
            float rr[4] = {r4.x*scl, r4.y*scl, r4.z*scl, r4.w*scl};
            float gg[4] = {g4.x*scl, g4.y*scl, g4.z*scl, g4.w*scl};
            float bl[4] = {b4.x*scl, b4.y*scl, b4.z*scl, b4.w*scl};
            float f = 0.1f + 1.8f*m;
            #pragma unroll
            for (int k = 0; k < 4; k++){
                float g = 0.299f*rr[k] + 0.587f*gg[k] + 0.114f*bl[k];
                o[k] = clip255(g + f*(iv[k] - g));
            }
            break; }
        case 7: {
            float f = 0.1f + 1.8f*m;
            #pragma unroll
            for (int k = 0; k < 4; k++){
                int xx = x + k;
                if (y == 0 || y == HGT-1 || xx == 0 || xx == WID-1) o[k] = iv[k];
                else {
                    int q = p + k;
                    float s8 = pl[q-WID-1] + pl[q-WID] + pl[q-WID+1]
                             + pl[q-1]     + pl[q+1]
                             + pl[q+WID-1] + pl[q+WID] + pl[q+WID+1];
                    float blur = (s8*scl + 5.f*iv[k]) * (1.f/13.f);
                    o[k] = clip255(blur + f*(iv[k] - blur));
                }
            }
            break; }
        case 8: {
            float mu = st[0];
            float f = 0.1f + 1.8f*m;
            #pragma unroll
            for (int k = 0; k < 4; k++) o[k] = clip255(mu + f*(iv[k] - mu));
            break; }
        case 9: {
            float thr = 256.f*m;
            #pragma unroll
            for (int k = 0; k < 4; k++) o[k] = (iv[k] < thr) ? iv[k] : 255.f - iv[k];
            break; }
        case 10: {
            float q = exp2f(rintf(4.f*m));
            #pragma unroll
            for (int k = 0; k < 4; k++) o[k] = floorf(iv[k]/q)*q;
            break; }
        case 11: {
            #pragma unroll
            for (int k = 0; k < 4; k++){
                int ivi = min(max((int)rintf(iv[k]), 0), 255);
                o[k] = st[16 + c*256 + ivi];
            }
            break; }
        case 12: {
            float lo = st[1+c], hi = st[4+c];
            float sc = 255.f / fmaxf(hi - lo, 1e-6f);
            #pragma unroll
            for (int k = 0; k < 4; k++)
                o[k] = (hi > lo) ? clip255((iv[k] - lo) * sc) : iv[k];
            break; }
        default:
            #pragma unroll
            for (int k = 0; k < 4; k++) o[k] = iv[k];
            break;
        }
    }

    float4 w;
    if (finalOut){
        w.x = fminf(fmaxf(o[0]*(1.f/255.f), 0.f), 1.f);
        w.y = fminf(fmaxf(o[1]*(1.f/255.f), 0.f), 1.f);
        w.z = fminf(fmaxf(o[2]*(1.f/255.f), 0.f), 1.f);
        w.w = fminf(fmaxf(o[3]*(1.f/255.f), 0.f), 1.f);
    } else {
        w.x = o[0]; w.y = o[1]; w.z = o[2]; w.w = o[3];
    }
    *(float4*)(dst + idx) = w;

    // fused next-depth stats accumulation on the values just written
    if (doStats){
        int jn = opiN[b];
        if (maskN[b] && (jn == 8 || jn == 11 || jn == 12)){
            const float GW[3] = {0.299f, 0.587f, 0.114f};
            if (jn == 8){
                float s4 = (o[0] + o[1]) + (o[2] + o[3]);
                float tot = blk_reduce(s4, red, tid, 0);
                if (tid == 0) psumN[blockIdx.x] = tot * GW[c];
            } else if (jn == 12){
                float lo = fminf(fminf(o[0],o[1]), fminf(o[2],o[3]));
                float hi = fmaxf(fmaxf(o[0],o[1]), fmaxf(o[2],o[3]));
                float l = blk_reduce(lo, red, tid, 1);
                if (tid == 0) pminN[blockIdx.x] = l;
                float h = blk_reduce(hi, red, tid, 2);
                if (tid == 0) pmaxN[blockIdx.x] = h;
            } else {
                sh[tid] = 0;
                __syncthreads();
                #pragma unroll
                for (int k = 0; k < 4; k++){
                    int ivi = min(max((int)rintf(o[k]), 0), 255);
                    atomicAdd(&sh[ivi], 1);
                }
                __syncthreads();
                int v = sh[tid];
                if (v) atomicAdd(&histN[b*768 + c*256 + tid], v);
            }
        }
    }
}

extern "C" void kernel_launch(void* const* d_in, const int* in_sizes, int n_in,
                              void* d_out, int out_size, void* d_ws, size_t ws_size,
                              hipStream_t stream) {
    const float* x    = (const float*)d_in[0];
    const float* ra   = (const float*)d_in[1];
    const int*   op   = (const int*)d_in[2];
    const int*   mask = (const int*)d_in[3];
    float* out = (float*)d_out;

    float* wsf    = (float*)d_ws;
    float* scale  = wsf;                          // [0]
    float* pmaxA  = wsf + 64;                     // [64, 2112)
    float* psum0  = wsf + 2112;                   // [2112, 4160)
    float* pmin0  = wsf + 4160;                   // 6144 -> [4160, 10304)
    float* pmax0  = wsf + 10304;                  // 6144 -> [10304, 16448)
    int*   phist0 = (int*)(wsf + 16448);          // 2048*1536 -> [16448, 3162176)
    int*   hist1  = (int*)(wsf + 3162176);        // 49152 -> [3162176, 3211328)
    float* psum1  = wsf + 3211328;                // 9408 -> [3211328, 3220736)
    float* pmin1  = wsf + 3220736;                // 9408
    float* pmax1  = wsf + 3230144;                // 9408
    float* stats0 = wsf + 3239552;                // 50176
    float* stats1 = wsf + 3289728;                // 50176
    float* inter  = wsf + 3342336;                // 9,633,792 floats (38.5 MB)

    const int N = NB * CHW;                       // 9,633,792

    pass0_kernel<<<NB*SPLIT, 256, 0, stream>>>(x, op, mask, pmaxA, psum0, pmin0, pmax0, phist0, hist1);
    fin0_kernel <<<NB, 256, 0, stream>>>(op, mask, pmaxA, psum0, pmin0, pmax0, phist0, scale, stats0);
    apply_kernel<<<N/1024, 256, 0, stream>>>(x, inter, op, ra, mask, scale, stats0,
                                             op + NB, mask + NB, psum1, pmin1, pmax1, hist1,
                                             1, 0, 1);
    fin1_kernel <<<NB, 256, 0, stream>>>(op + NB, mask + NB, psum1, pmin1, pmax1, hist1, stats1);
    apply_kernel<<<N/1024, 256, 0, stream>>>(inter, out, op + NB, ra + NB, mask + NB, scale, stats1,
                                             nullptr, nullptr, nullptr, nullptr, nullptr, nullptr,
                                             0, 1, 0);
}